// Round 2
// baseline (371.964 us; speedup 1.0000x reference)
//
#include <hip/hip_runtime.h>

// Two-layer cached GCN. Round 8:
// (a) agg layer-2 reverted to the round-0 proven form (32 lanes/row, half4v,
//     no nontemporal hints) — the 16-lane+nt rewrite cost +4us/+12MB fetch.
// (b) gemm-2 fused into agg-1 (k_agg_gemm): aggregate -> relu/bias/dinv ->
//     fp16 LDS tile (16x136) -> 8 waves x MFMA 16x16x32 vs W2t (L1-resident)
//     -> ts2. Saves 25MB h-write + 25.6MB h-read + one dispatch.
//     Buffers: gemm1 writes ts1 into d_out (fp16); fused reads d_out, writes
//     ts2 into ws t; final agg reads t, writes fp32 out over d_out.
// (c) dispatches 15 -> 10: k_prep does both W transposes + zeroing;
//     bincount+bucket-scan and scan1+scan2 fused via last-block pattern
//     (device-scope atomics on both writer and reader side for cross-XCD
//     coherence); binfill CH 8192->4096 (391 blocks, 32KB LDS -> occupancy).

#define BKT_SHIFT 7
#define BKT_NODES 128
#define CH 4096
#define MAXBKT 1024

typedef _Float16 half4v __attribute__((ext_vector_type(4)));
typedef _Float16 half8v __attribute__((ext_vector_type(8)));
typedef float float4v __attribute__((ext_vector_type(4)));

// ---------------- prep: W1/W2 -> fp16 transposed, zero bcnt + done-counters ----
__global__ __launch_bounds__(256) void k_prep(const float* __restrict__ W1,
                                              const float* __restrict__ W2,
                                              _Float16* __restrict__ wt1,
                                              _Float16* __restrict__ wt2,
                                              int* __restrict__ bcnt,
                                              int* __restrict__ dcnt, int nbkt) {
    int i = blockIdx.x * 256 + threadIdx.x;   // 0..32767
    if (i < 16384) {
        int k = i >> 7, c = i & 127;
        wt1[c * 128 + k] = (_Float16)W1[i];
    } else {
        int j = i - 16384;
        int k = j >> 7, c = j & 127;
        wt2[c * 128 + k] = (_Float16)W2[j];
    }
    if (i < nbkt) bcnt[i] = 0;
    if (i < 2) dcnt[i] = 0;
}

// ---------------- bucket histogram + last-block exclusive scan ----------------
__global__ __launch_bounds__(256) void k_bincount_scan(const int* __restrict__ dst,
                                                       int* __restrict__ bcnt,
                                                       int* __restrict__ bofs,
                                                       int* __restrict__ bcur,
                                                       int* __restrict__ dcnt,
                                                       int E, int nbkt, int nblocks) {
    __shared__ int sh[MAXBKT];
    const int t = threadIdx.x;
    for (int i = t; i < nbkt; i += 256) sh[i] = 0;
    __syncthreads();
    for (long long e = (long long)blockIdx.x * 256 + t; e < E;
         e += (long long)nblocks * 256)
        atomicAdd(&sh[dst[e] >> BKT_SHIFT], 1);
    __syncthreads();
    for (int i = t; i < nbkt; i += 256)
        if (sh[i]) atomicAdd(&bcnt[i], sh[i]);   // device-scope, coherent
    __threadfence();
    __syncthreads();
    __shared__ int last;
    if (t == 0) last = (atomicAdd(&dcnt[0], 1) == nblocks - 1);
    __syncthreads();
    if (!last) return;
    __threadfence();
    // last block: exclusive scan of bcnt[0..nbkt) (nbkt <= 1024), 4/thread.
    // coherent reads via atomicAdd(p,0).
    int v[4];
    int s = 0;
    for (int k = 0; k < 4; k++) {
        int idx = t * 4 + k;
        v[k] = (idx < nbkt) ? atomicAdd(&bcnt[idx], 0) : 0;
        s += v[k];
    }
    __syncthreads();
    int x = s;
    sh[t] = x;
    __syncthreads();
    for (int o = 1; o < 256; o <<= 1) {
        int y = (t >= o) ? sh[t - o] : 0;
        __syncthreads();
        x += y;
        sh[t] = x;
        __syncthreads();
    }
    int run = x - s;
    for (int k = 0; k < 4; k++) {
        int idx = t * 4 + k;
        if (idx < nbkt) { bofs[idx] = run; bcur[idx] = run; }
        run += v[k];
    }
    if (t == 0) bofs[nbkt] = E;
}

// ---------------- bulk-reservation bin fill ----------------
__global__ __launch_bounds__(256) void k_binfill(const int* __restrict__ src,
                                                 const int* __restrict__ dst,
                                                 int* __restrict__ bcur,
                                                 unsigned* __restrict__ recs,
                                                 int E, int nbkt) {
    __shared__ unsigned stage[CH];          // 16 KB
    __shared__ unsigned short stageb[CH];   // 8 KB
    __shared__ int cnt[MAXBKT];             // 4 KB
    __shared__ int base[MAXBKT];            // 4 KB
    const int t = threadIdx.x;
    const long long c0 = (long long)blockIdx.x * CH;

    for (int i = t; i < nbkt; i += 256) cnt[i] = 0;
    __syncthreads();

    for (int k = 0; k < CH / 256; k++) {
        int i = k * 256 + t;
        long long e = c0 + i;
        if (e < E) {
            int d = dst[e];
            int b = d >> BKT_SHIFT;
            stage[i] = ((unsigned)(d & (BKT_NODES - 1)) << 17) | (unsigned)src[e];
            stageb[i] = (unsigned short)b;
            atomicAdd(&cnt[b], 1);
        }
    }
    __syncthreads();

    for (int i = t; i < nbkt; i += 256) {
        int c = cnt[i];
        base[i] = c ? atomicAdd(&bcur[i], c) : 0;
        cnt[i] = 0;
    }
    __syncthreads();

    for (int k = 0; k < CH / 256; k++) {
        int i = k * 256 + t;
        if (c0 + i < E) {
            int b = stageb[i];
            int p = base[b] + atomicAdd(&cnt[b], 1);
            recs[p] = stage[i];
        }
    }
}

__global__ __launch_bounds__(256) void k_deg_bins(const unsigned* __restrict__ recs,
                                                  const int* __restrict__ bofs,
                                                  int* __restrict__ deg, int n) {
    __shared__ int cnt[BKT_NODES];
    const int b = blockIdx.x, t = threadIdx.x;
    if (t < BKT_NODES) cnt[t] = 0;
    __syncthreads();
    const int beg = bofs[b], end = bofs[b + 1];
    for (int j = beg + t; j < end; j += 256)
        atomicAdd(&cnt[recs[j] >> 17], 1);
    __syncthreads();
    const int d0 = b << BKT_SHIFT;
    if (t < BKT_NODES && d0 + t < n) deg[d0 + t] = cnt[t];
}

// ---------------- scan1 + last-block scan2 ----------------
__global__ __launch_bounds__(256) void k_scan12(const int* __restrict__ deg,
                                                float* __restrict__ dinv,
                                                int* __restrict__ ofs,
                                                int* __restrict__ sums,
                                                int* __restrict__ dcnt,
                                                int n, int nblocks) {
    __shared__ int sh[256];
    const int t = threadIdx.x;
    const int i = blockIdx.x * 256 + t;
    int v = (i < n) ? deg[i] : 0;
    if (i < n) dinv[i] = rsqrtf((float)v + 1.0f);
    int x = v;
    sh[t] = x;
    __syncthreads();
    for (int o = 1; o < 256; o <<= 1) {
        int y = (t >= o) ? sh[t - o] : 0;
        __syncthreads();
        x += y;
        sh[t] = x;
        __syncthreads();
    }
    if (i < n) ofs[i] = x - v;
    if (t == 255) atomicExch(&sums[blockIdx.x], x);  // device-coherent publish
    __threadfence();
    __syncthreads();
    __shared__ int last;
    if (t == 0) last = (atomicAdd(&dcnt[1], 1) == nblocks - 1);
    __syncthreads();
    if (!last) return;
    __threadfence();
    // exclusive scan of sums[0..nblocks) (nblocks <= 1024), 4/thread
    int vv[4];
    int s = 0;
    for (int k = 0; k < 4; k++) {
        int idx = t * 4 + k;
        vv[k] = (idx < nblocks) ? atomicAdd(&sums[idx], 0) : 0;
        s += vv[k];
    }
    __syncthreads();
    int xx = s;
    sh[t] = xx;
    __syncthreads();
    for (int o = 1; o < 256; o <<= 1) {
        int y = (t >= o) ? sh[t - o] : 0;
        __syncthreads();
        xx += y;
        sh[t] = xx;
        __syncthreads();
    }
    int run = xx - s;
    for (int k = 0; k < 4; k++) {
        int idx = t * 4 + k;
        if (idx < nblocks) sums[idx] = run;
        run += vv[k];
    }
}

__global__ void k_scan3(int* __restrict__ ofs, const int* __restrict__ sums, int n, int E) {
    int i = blockIdx.x * 256 + threadIdx.x;
    if (i < n) ofs[i] += sums[blockIdx.x];
    if (i == 0) ofs[n] = E;
}

__global__ __launch_bounds__(256) void k_fill_bins(const unsigned* __restrict__ recs,
                                                   const int* __restrict__ bofs,
                                                   const int* __restrict__ ofs,
                                                   int* __restrict__ col, int n) {
    __shared__ int cur[BKT_NODES];
    const int b = blockIdx.x, t = threadIdx.x;
    const int d0 = b << BKT_SHIFT;
    if (t < BKT_NODES) cur[t] = (d0 + t < n) ? ofs[d0 + t] : 0;
    __syncthreads();
    const int beg = bofs[b], end = bofs[b + 1];
    for (int j = beg + t; j < end; j += 256) {
        unsigned r = recs[j];
        int p = atomicAdd(&cur[r >> 17], 1);
        col[p] = (int)(r & 0x1FFFF);
    }
}

// ---------------- MFMA GEMM: ts[N x 128](fp16) = dinv[row] * (in @ W1) ------
// A fragments straight from global (read-once); only W in LDS; 4 blocks/CU.
__global__ __launch_bounds__(256, 4) void k_gemm_mfma(const float* __restrict__ in,
                                                      const _Float16* __restrict__ Wt,
                                                      const float* __restrict__ dinv,
                                                      _Float16* __restrict__ out, int n) {
    __shared__ _Float16 Bl[128][136];  // 34.8 KB
    const int t = threadIdx.x;
    const int row0 = blockIdx.x * 64;

    for (int i = t; i < 128 * 16; i += 256) {
        int r = i >> 4, c8 = i & 15;
        *(half8v*)&Bl[r][c8 * 8] = *(const half8v*)&Wt[r * 128 + c8 * 8];
    }
    __syncthreads();

    const int wave = t >> 6;
    const int lane = t & 63;
    const int m0 = wave * 16;
    const int ml = lane & 15;
    const int quad = lane >> 4;

    int r = row0 + m0 + ml;
    if (r >= n) r = n - 1;   // clamp: OOB rows compute garbage, never stored

    float4v acc[8] = {};
#pragma unroll
    for (int kc = 0; kc < 4; kc++) {
        const float* ap = in + (size_t)r * 128 + kc * 32 + quad * 8;
        float4v v0 = *(const float4v*)ap;
        float4v v1 = *(const float4v*)(ap + 4);
        half8v a;
#pragma unroll
        for (int k = 0; k < 4; k++) {
            a[k] = (_Float16)v0[k];
            a[4 + k] = (_Float16)v1[k];
        }
#pragma unroll
        for (int nt = 0; nt < 8; nt++) {
            half8v b = *(const half8v*)&Bl[nt * 16 + ml][kc * 32 + quad * 8];
            acc[nt] = __builtin_amdgcn_mfma_f32_16x16x32_f16(a, b, acc[nt], 0, 0, 0);
        }
    }

    int nr = n - row0;
    if (nr > 64) nr = 64;
#pragma unroll
    for (int reg = 0; reg < 4; reg++) {
        int rr = m0 + quad * 4 + reg;
        if (rr < nr) {
            float dv = dinv[row0 + rr];
#pragma unroll
            for (int nt = 0; nt < 8; nt++)
                out[(size_t)(row0 + rr) * 128 + nt * 16 + ml] =
                    (_Float16)(acc[nt][reg] * dv);
        }
    }
}

// ---------------- fused agg-1 + gemm-2 ----------------
// 512 threads = 16 rows x 32 lanes. Phase 1: round-0 CSR aggregation into
// fp32 regs; h = relu(b1 + dinv*acc) -> fp16 LDS tile hl[16][136].
// Phase 2: 8 waves, wave w = n-tile w; MFMA 16x16x32 over K=128 with B
// fragments from W2t global (32 KB, L1-resident); ts2 = dinv * (h @ W2).
__global__ __launch_bounds__(512, 4) void k_agg_gemm(const int* __restrict__ ofs,
                                                     const int* __restrict__ col,
                                                     const float* __restrict__ dinv,
                                                     const half4v* __restrict__ ts,
                                                     const float* __restrict__ bias,
                                                     const _Float16* __restrict__ Wt2,
                                                     _Float16* __restrict__ outt, int n) {
    __shared__ __align__(16) _Float16 hl[16][136];  // 4.35 KB
    const int t = threadIdx.x;
    const int row0 = blockIdx.x * 16;
    const int r16 = t >> 5;
    const int lane = t & 31;
    const int row = row0 + r16;

    float4 acc = make_float4(0.f, 0.f, 0.f, 0.f);
    float dd = 0.f;
    if (row < n) {
        dd = dinv[row];
        int beg = ofs[row];
        int end = ofs[row + 1];
        half4v sv = ts[(size_t)row * 32 + lane];
        acc.x = (float)sv[0]; acc.y = (float)sv[1];
        acc.z = (float)sv[2]; acc.w = (float)sv[3];
        int j = beg;
        for (; j + 3 < end; j += 4) {
            int s0 = col[j], s1 = col[j + 1], s2 = col[j + 2], s3 = col[j + 3];
            half4v v0 = ts[(size_t)s0 * 32 + lane];
            half4v v1 = ts[(size_t)s1 * 32 + lane];
            half4v v2 = ts[(size_t)s2 * 32 + lane];
            half4v v3 = ts[(size_t)s3 * 32 + lane];
            acc.x += (float)v0[0] + (float)v1[0] + (float)v2[0] + (float)v3[0];
            acc.y += (float)v0[1] + (float)v1[1] + (float)v2[1] + (float)v3[1];
            acc.z += (float)v0[2] + (float)v1[2] + (float)v2[2] + (float)v3[2];
            acc.w += (float)v0[3] + (float)v1[3] + (float)v2[3] + (float)v3[3];
        }
        for (; j < end; j++) {
            half4v v = ts[(size_t)col[j] * 32 + lane];
            acc.x += (float)v[0];
            acc.y += (float)v[1];
            acc.z += (float)v[2];
            acc.w += (float)v[3];
        }
    }
    float4 bv = *(const float4*)&bias[lane * 4];
    half4v hv;
    hv[0] = (_Float16)fmaxf(bv.x + dd * acc.x, 0.f);
    hv[1] = (_Float16)fmaxf(bv.y + dd * acc.y, 0.f);
    hv[2] = (_Float16)fmaxf(bv.z + dd * acc.z, 0.f);
    hv[3] = (_Float16)fmaxf(bv.w + dd * acc.w, 0.f);
    *(half4v*)&hl[r16][lane * 4] = hv;
    __syncthreads();

    const int w = t >> 6;          // 0..7 = n-tile
    const int l = t & 63;
    const int ml = l & 15;
    const int quad = l >> 4;

    float4v acc2 = {};
#pragma unroll
    for (int kc = 0; kc < 4; kc++) {
        half8v a = *(const half8v*)&hl[ml][kc * 32 + quad * 8];
        half8v b = *(const half8v*)&Wt2[(size_t)(w * 16 + ml) * 128 + kc * 32 + quad * 8];
        acc2 = __builtin_amdgcn_mfma_f32_16x16x32_f16(a, b, acc2, 0, 0, 0);
    }
#pragma unroll
    for (int reg = 0; reg < 4; reg++) {
        int node = row0 + quad * 4 + reg;
        if (node < n) {
            float dv = dinv[node];
            outt[(size_t)node * 128 + w * 16 + ml] = (_Float16)(acc2[reg] * dv);
        }
    }
}

// ---------------- CSR aggregation, layer 2 (round-0 proven form) ----------------
__global__ __launch_bounds__(256) void k_agg_csr32(const int* __restrict__ ofs,
                                                   const int* __restrict__ col,
                                                   const float* __restrict__ dinv,
                                                   const half4v* __restrict__ ts,
                                                   const float* __restrict__ bias,
                                                   float* __restrict__ out, int n) {
    int gid = blockIdx.x * 256 + threadIdx.x;
    int row = gid >> 5;
    int lane = gid & 31;
    if (row >= n) return;

    float dd = dinv[row];
    int beg = ofs[row];
    int end = ofs[row + 1];

    half4v sv = ts[(size_t)row * 32 + lane];
    float4 acc = make_float4((float)sv[0], (float)sv[1], (float)sv[2], (float)sv[3]);

    int j = beg;
    for (; j + 3 < end; j += 4) {
        int s0 = col[j], s1 = col[j + 1], s2 = col[j + 2], s3 = col[j + 3];
        half4v v0 = ts[(size_t)s0 * 32 + lane];
        half4v v1 = ts[(size_t)s1 * 32 + lane];
        half4v v2 = ts[(size_t)s2 * 32 + lane];
        half4v v3 = ts[(size_t)s3 * 32 + lane];
        acc.x += (float)v0[0] + (float)v1[0] + (float)v2[0] + (float)v3[0];
        acc.y += (float)v0[1] + (float)v1[1] + (float)v2[1] + (float)v3[1];
        acc.z += (float)v0[2] + (float)v1[2] + (float)v2[2] + (float)v3[2];
        acc.w += (float)v0[3] + (float)v1[3] + (float)v2[3] + (float)v3[3];
    }
    for (; j < end; j++) {
        half4v v = ts[(size_t)col[j] * 32 + lane];
        acc.x += (float)v[0];
        acc.y += (float)v[1];
        acc.z += (float)v[2];
        acc.w += (float)v[3];
    }

    float4 bv = *(const float4*)&bias[lane * 4];
    float4 o;
    o.x = bv.x + dd * acc.x;
    o.y = bv.y + dd * acc.y;
    o.z = bv.z + dd * acc.z;
    o.w = bv.w + dd * acc.w;
    *(float4*)&out[(size_t)row * 128 + lane * 4] = o;
}

extern "C" void kernel_launch(void* const* d_in, const int* in_sizes, int n_in,
                              void* d_out, int out_size, void* d_ws, size_t ws_size,
                              hipStream_t stream) {
    const int N = in_sizes[0] / 128;
    const int E = in_sizes[1] / 2;
    const float* x  = (const float*)d_in[0];
    const int*   ei = (const int*)d_in[1];
    const float* W1 = (const float*)d_in[2];
    const float* b1 = (const float*)d_in[3];
    const float* W2 = (const float*)d_in[4];
    const float* b2 = (const float*)d_in[5];

    const int* src = ei;
    const int* dst = ei + E;

    const int nb_n  = (N + 255) / 256;
    const int NBKT  = (N + BKT_NODES - 1) / BKT_NODES;

    // ---- workspace layout ----
    _Float16* t    = (_Float16*)d_ws;            // N*128 (ts2)
    _Float16* wt1  = t + (size_t)N * 128;        // 16384
    _Float16* wt2  = wt1 + 16384;                // 16384
    float*    dinv = (float*)(wt2 + 16384);      // N
    int*      ofs  = (int*)(dinv + N);           // N+1
    int*      deg  = ofs + N + 1;                // N
    int*      sums = deg + N;                    // nb_n (padded)
    unsigned* recs = (unsigned*)(sums + ((nb_n + 255) & ~255)); // E
    int*      col  = (int*)(recs + E);           // E
    int*      bofs = col + E;                    // NBKT+1
    int*      bcur = bofs + NBKT + 1;            // NBKT
    int*      bcnt = bcur + NBKT;                // NBKT
    int*      dcnt = bcnt + NBKT;                // 2 (done counters)

    // ts1 (layer-1 dense transform, fp16) lives in d_out's front half;
    // final fp32 out overwrites d_out afterwards (by then ts1 is dead).
    _Float16* ts1 = (_Float16*)d_out;
    float*    out = (float*)d_out;

    const int nb_g = (N + 63) / 64;
    const int nb_f = (N + 15) / 16;
    const int nb_a = (int)(((long long)N * 32 + 255) / 256);
    const int nb_c = (int)(((long long)E + CH - 1) / CH);

    // ---- prep + binning + CSR build ----
    k_prep<<<128, 256, 0, stream>>>(W1, W2, wt1, wt2, bcnt, dcnt, NBKT);
    k_bincount_scan<<<256, 256, 0, stream>>>(dst, bcnt, bofs, bcur, dcnt, E, NBKT, 256);
    k_binfill<<<nb_c, 256, 0, stream>>>(src, dst, bcur, recs, E, NBKT);
    k_deg_bins<<<NBKT, 256, 0, stream>>>(recs, bofs, deg, N);
    k_scan12<<<nb_n, 256, 0, stream>>>(deg, dinv, ofs, sums, dcnt, N, nb_n);
    k_scan3<<<nb_n, 256, 0, stream>>>(ofs, sums, N, E);
    k_fill_bins<<<NBKT, 256, 0, stream>>>(recs, bofs, ofs, col, N);

    // ---- layer 1 GEMM: ts1 = dinv * (x@W1)  (fp16, into d_out) ----
    k_gemm_mfma<<<nb_g, 256, 0, stream>>>(x, wt1, dinv, ts1, N);

    // ---- fused agg-1 + gemm-2: ts2 = dinv * (relu(b1 + dinv*(agg ts1)) @ W2) ----
    k_agg_gemm<<<nb_f, 512, 0, stream>>>(ofs, col, dinv, (const half4v*)ts1, b1, wt2, t, N);

    // ---- layer 2 agg: out = b2 + dinv * (ts2[d] + sum ts2[col]) ----
    k_agg_csr32<<<nb_a, 256, 0, stream>>>(ofs, col, dinv, (const half4v*)t, b2, out, N);
}

// Round 3
// 328.061 us; speedup vs baseline: 1.1338x; 1.1338x over previous
//
#include <hip/hip_runtime.h>

// Two-layer cached GCN. Round 9:
// (a) un-fuse agg+gemm (round-8 fusion cost +19us: barrier couples 16
//     variable-degree rows -> BW 3.7->2.36 TB/s). Back to separate kernels,
//     both aggs in the round-0-proven 32-lane/half4v form; layer-1 agg keeps
//     the proven fp16+relu output (h16), gemm-2 reads fp16.
// (b) CSR-build collapse: since ofs = exclusive-scan(deg) and records are
//     bucket-grouped, bucket_base[b] == bofs[b]. So deg_bins+scan1+scan2+
//     scan3+fill_bins fuse into ONE per-bucket kernel (k_fill_all):
//     LDS histogram -> 128-wide intra-bucket scan -> ofs/dinv -> scatter col.
//     13 -> 8 dispatches, 3 fewer passes over recs, no single-block kernels.
// (c) binfill back to proven CH=8192.

#define BKT_SHIFT 7
#define BKT_NODES 128
#define CH 8192
#define MAXBKT 1024

typedef _Float16 half4v __attribute__((ext_vector_type(4)));
typedef _Float16 half8v __attribute__((ext_vector_type(8)));
typedef float float4v __attribute__((ext_vector_type(4)));

// ---------------- prep: W1/W2 -> fp16 transposed, zero bcnt + done-counter ----
__global__ __launch_bounds__(256) void k_prep(const float* __restrict__ W1,
                                              const float* __restrict__ W2,
                                              _Float16* __restrict__ wt1,
                                              _Float16* __restrict__ wt2,
                                              int* __restrict__ bcnt,
                                              int* __restrict__ dcnt, int nbkt) {
    int i = blockIdx.x * 256 + threadIdx.x;   // 0..32767
    if (i < 16384) {
        int k = i >> 7, c = i & 127;
        wt1[c * 128 + k] = (_Float16)W1[i];
    } else {
        int j = i - 16384;
        int k = j >> 7, c = j & 127;
        wt2[c * 128 + k] = (_Float16)W2[j];
    }
    if (i < nbkt) bcnt[i] = 0;
    if (i < 2) dcnt[i] = 0;
}

// ---------------- bucket histogram + last-block exclusive scan ----------------
__global__ __launch_bounds__(256) void k_bincount_scan(const int* __restrict__ dst,
                                                       int* __restrict__ bcnt,
                                                       int* __restrict__ bofs,
                                                       int* __restrict__ bcur,
                                                       int* __restrict__ dcnt,
                                                       int E, int nbkt, int nblocks) {
    __shared__ int sh[MAXBKT];
    const int t = threadIdx.x;
    for (int i = t; i < nbkt; i += 256) sh[i] = 0;
    __syncthreads();
    for (long long e = (long long)blockIdx.x * 256 + t; e < E;
         e += (long long)nblocks * 256)
        atomicAdd(&sh[dst[e] >> BKT_SHIFT], 1);
    __syncthreads();
    for (int i = t; i < nbkt; i += 256)
        if (sh[i]) atomicAdd(&bcnt[i], sh[i]);   // device-scope, coherent
    __threadfence();
    __syncthreads();
    __shared__ int last;
    if (t == 0) last = (atomicAdd(&dcnt[0], 1) == nblocks - 1);
    __syncthreads();
    if (!last) return;
    __threadfence();
    // last block: exclusive scan of bcnt[0..nbkt), 4/thread, coherent reads.
    int v[4];
    int s = 0;
    for (int k = 0; k < 4; k++) {
        int idx = t * 4 + k;
        v[k] = (idx < nbkt) ? atomicAdd(&bcnt[idx], 0) : 0;
        s += v[k];
    }
    __syncthreads();
    int x = s;
    sh[t] = x;
    __syncthreads();
    for (int o = 1; o < 256; o <<= 1) {
        int y = (t >= o) ? sh[t - o] : 0;
        __syncthreads();
        x += y;
        sh[t] = x;
        __syncthreads();
    }
    int run = x - s;
    for (int k = 0; k < 4; k++) {
        int idx = t * 4 + k;
        if (idx < nbkt) { bofs[idx] = run; bcur[idx] = run; }
        run += v[k];
    }
    if (t == 0) bofs[nbkt] = E;
}

// ---------------- bulk-reservation bin fill (proven CH=8192 config) ----------
__global__ __launch_bounds__(256) void k_binfill(const int* __restrict__ src,
                                                 const int* __restrict__ dst,
                                                 int* __restrict__ bcur,
                                                 unsigned* __restrict__ recs,
                                                 int E, int nbkt) {
    __shared__ unsigned stage[CH];          // 32 KB
    __shared__ unsigned short stageb[CH];   // 16 KB
    __shared__ int cnt[MAXBKT];             // 4 KB
    __shared__ int base[MAXBKT];            // 4 KB
    const int t = threadIdx.x;
    const long long c0 = (long long)blockIdx.x * CH;

    for (int i = t; i < nbkt; i += 256) cnt[i] = 0;
    __syncthreads();

    for (int k = 0; k < CH / 256; k++) {
        int i = k * 256 + t;
        long long e = c0 + i;
        if (e < E) {
            int d = dst[e];
            int b = d >> BKT_SHIFT;
            stage[i] = ((unsigned)(d & (BKT_NODES - 1)) << 17) | (unsigned)src[e];
            stageb[i] = (unsigned short)b;
            atomicAdd(&cnt[b], 1);
        }
    }
    __syncthreads();

    for (int i = t; i < nbkt; i += 256) {
        int c = cnt[i];
        base[i] = c ? atomicAdd(&bcur[i], c) : 0;
        cnt[i] = 0;
    }
    __syncthreads();

    for (int k = 0; k < CH / 256; k++) {
        int i = k * 256 + t;
        if (c0 + i < E) {
            int b = stageb[i];
            int p = base[b] + atomicAdd(&cnt[b], 1);
            recs[p] = stage[i];
        }
    }
}

// ---------------- fused deg + scan + CSR fill ----------------
// bucket_base[b] == bofs[b] (records are bucket-grouped and ofs is the
// exclusive scan of deg), so everything after binfill is per-bucket-local:
// histogram recs -> intra-bucket exclusive scan (128 wide) -> ofs, dinv,
// cur -> scatter col. One pass over recs instead of three.
__global__ __launch_bounds__(256) void k_fill_all(const unsigned* __restrict__ recs,
                                                  const int* __restrict__ bofs,
                                                  float* __restrict__ dinv,
                                                  int* __restrict__ ofs,
                                                  int* __restrict__ col,
                                                  int n, int E) {
    __shared__ int cnt[BKT_NODES];
    __shared__ int sc[BKT_NODES];
    const int b = blockIdx.x, t = threadIdx.x;
    const int beg = bofs[b], end = bofs[b + 1];

    if (t < BKT_NODES) cnt[t] = 0;
    __syncthreads();
    for (int j = beg + t; j < end; j += 256)
        atomicAdd(&cnt[recs[j] >> 17], 1);
    __syncthreads();

    // exclusive scan of cnt[0..128) (Hillis-Steele; all 256 threads at barriers)
    int v = 0, x = 0;
    if (t < BKT_NODES) { v = cnt[t]; x = v; sc[t] = x; }
    __syncthreads();
    for (int o = 1; o < BKT_NODES; o <<= 1) {
        int y = (t >= o && t < BKT_NODES) ? sc[t - o] : 0;
        __syncthreads();
        if (t < BKT_NODES) { x += y; sc[t] = x; }
        __syncthreads();
    }

    const int d0 = b << BKT_SHIFT;
    if (t < BKT_NODES) {
        int off = beg + x - v;
        int node = d0 + t;
        if (node < n) {
            ofs[node] = off;
            dinv[node] = rsqrtf((float)v + 1.0f);
        }
        cnt[t] = off;   // becomes cur
    }
    if (b == 0 && t == 0) ofs[n] = E;
    __syncthreads();

    for (int j = beg + t; j < end; j += 256) {
        unsigned r = recs[j];
        int p = atomicAdd(&cnt[r >> 17], 1);
        col[p] = (int)(r & 0x1FFFF);
    }
}

// ---------------- MFMA GEMM: ts[N x 128](fp16) = dinv[row] * (in @ W) ------
// A fragments straight from global (read-once); only W in LDS; 4 blocks/CU.
template <int IN_HALF>
__global__ __launch_bounds__(256, 4) void k_gemm_mfma(const void* __restrict__ inp,
                                                      const _Float16* __restrict__ Wt,
                                                      const float* __restrict__ dinv,
                                                      _Float16* __restrict__ out, int n) {
    __shared__ _Float16 Bl[128][136];  // 34.8 KB
    const int t = threadIdx.x;
    const int row0 = blockIdx.x * 64;

    for (int i = t; i < 128 * 16; i += 256) {
        int r = i >> 4, c8 = i & 15;
        *(half8v*)&Bl[r][c8 * 8] = *(const half8v*)&Wt[r * 128 + c8 * 8];
    }
    __syncthreads();

    const int wave = t >> 6;
    const int lane = t & 63;
    const int m0 = wave * 16;
    const int ml = lane & 15;
    const int quad = lane >> 4;

    int r = row0 + m0 + ml;
    if (r >= n) r = n - 1;   // clamp: OOB rows compute garbage, never stored

    float4v acc[8] = {};
#pragma unroll
    for (int kc = 0; kc < 4; kc++) {
        half8v a;
        if (IN_HALF) {
            a = *(const half8v*)((const _Float16*)inp + (size_t)r * 128 + kc * 32 + quad * 8);
        } else {
            const float* ap = (const float*)inp + (size_t)r * 128 + kc * 32 + quad * 8;
            float4v v0 = *(const float4v*)ap;
            float4v v1 = *(const float4v*)(ap + 4);
#pragma unroll
            for (int k = 0; k < 4; k++) {
                a[k] = (_Float16)v0[k];
                a[4 + k] = (_Float16)v1[k];
            }
        }
#pragma unroll
        for (int nt = 0; nt < 8; nt++) {
            half8v bfr = *(const half8v*)&Bl[nt * 16 + ml][kc * 32 + quad * 8];
            acc[nt] = __builtin_amdgcn_mfma_f32_16x16x32_f16(a, bfr, acc[nt], 0, 0, 0);
        }
    }

    int nr = n - row0;
    if (nr > 64) nr = 64;
#pragma unroll
    for (int reg = 0; reg < 4; reg++) {
        int rr = m0 + quad * 4 + reg;
        if (rr < nr) {
            float dv = dinv[row0 + rr];
#pragma unroll
            for (int nt = 0; nt < 8; nt++)
                out[(size_t)(row0 + rr) * 128 + nt * 16 + ml] =
                    (_Float16)(acc[nt][reg] * dv);
        }
    }
}

// ---------------- CSR aggregation (round-0 proven 32-lane form) ----------------
// OUT_HALF=1: out = relu(b + dinv*acc) as fp16 (layer-1 hidden; exact since
// gemm-2 re-quantizes to fp16 anyway and relu commutes with rounding).
template <int OUT_HALF>
__global__ __launch_bounds__(256) void k_agg_csr(const int* __restrict__ ofs,
                                                 const int* __restrict__ col,
                                                 const float* __restrict__ dinv,
                                                 const half4v* __restrict__ ts,
                                                 const float* __restrict__ bias,
                                                 void* __restrict__ outp, int n) {
    int gid = blockIdx.x * 256 + threadIdx.x;
    int row = gid >> 5;
    int lane = gid & 31;
    if (row >= n) return;

    float dd = dinv[row];
    int beg = ofs[row];
    int end = ofs[row + 1];

    half4v sv = ts[(size_t)row * 32 + lane];
    float4 acc = make_float4((float)sv[0], (float)sv[1], (float)sv[2], (float)sv[3]);

    int j = beg;
    for (; j + 3 < end; j += 4) {
        int s0 = col[j], s1 = col[j + 1], s2 = col[j + 2], s3 = col[j + 3];
        half4v v0 = ts[(size_t)s0 * 32 + lane];
        half4v v1 = ts[(size_t)s1 * 32 + lane];
        half4v v2 = ts[(size_t)s2 * 32 + lane];
        half4v v3 = ts[(size_t)s3 * 32 + lane];
        acc.x += (float)v0[0] + (float)v1[0] + (float)v2[0] + (float)v3[0];
        acc.y += (float)v0[1] + (float)v1[1] + (float)v2[1] + (float)v3[1];
        acc.z += (float)v0[2] + (float)v1[2] + (float)v2[2] + (float)v3[2];
        acc.w += (float)v0[3] + (float)v1[3] + (float)v2[3] + (float)v3[3];
    }
    for (; j < end; j++) {
        half4v v = ts[(size_t)col[j] * 32 + lane];
        acc.x += (float)v[0];
        acc.y += (float)v[1];
        acc.z += (float)v[2];
        acc.w += (float)v[3];
    }

    float4 bv = *(const float4*)&bias[lane * 4];
    if (OUT_HALF) {
        half4v hv;
        hv[0] = (_Float16)fmaxf(bv.x + dd * acc.x, 0.f);
        hv[1] = (_Float16)fmaxf(bv.y + dd * acc.y, 0.f);
        hv[2] = (_Float16)fmaxf(bv.z + dd * acc.z, 0.f);
        hv[3] = (_Float16)fmaxf(bv.w + dd * acc.w, 0.f);
        ((half4v*)outp)[(size_t)row * 32 + lane] = hv;
    } else {
        float4 o;
        o.x = bv.x + dd * acc.x;
        o.y = bv.y + dd * acc.y;
        o.z = bv.z + dd * acc.z;
        o.w = bv.w + dd * acc.w;
        *(float4*)&((float*)outp)[(size_t)row * 128 + lane * 4] = o;
    }
}

extern "C" void kernel_launch(void* const* d_in, const int* in_sizes, int n_in,
                              void* d_out, int out_size, void* d_ws, size_t ws_size,
                              hipStream_t stream) {
    const int N = in_sizes[0] / 128;
    const int E = in_sizes[1] / 2;
    const float* x  = (const float*)d_in[0];
    const int*   ei = (const int*)d_in[1];
    const float* W1 = (const float*)d_in[2];
    const float* b1 = (const float*)d_in[3];
    const float* W2 = (const float*)d_in[4];
    const float* b2 = (const float*)d_in[5];

    const int* src = ei;
    const int* dst = ei + E;

    const int NBKT = (N + BKT_NODES - 1) / BKT_NODES;

    // ---- workspace layout ----
    _Float16* t    = (_Float16*)d_ws;            // N*128 (ts, reused per layer)
    _Float16* wt1  = t + (size_t)N * 128;        // 16384
    _Float16* wt2  = wt1 + 16384;                // 16384
    float*    dinv = (float*)(wt2 + 16384);      // N
    int*      ofs  = (int*)(dinv + N);           // N+1
    unsigned* recs = (unsigned*)(ofs + ((N + 2 + 255) & ~255)); // E
    int*      col  = (int*)(recs + E);           // E
    int*      bofs = col + E;                    // NBKT+1
    int*      bcur = bofs + NBKT + 1;            // NBKT
    int*      bcnt = bcur + NBKT;                // NBKT
    int*      dcnt = bcnt + NBKT;                // 2 (done counters)

    // layer-1 hidden (fp16, relu applied) in front half of d_out;
    // final fp32 out overwrites d_out afterwards (h16 dead by then).
    _Float16* h16 = (_Float16*)d_out;
    float*    out = (float*)d_out;

    const int nb_g = (N + 63) / 64;
    const int nb_a = (int)(((long long)N * 32 + 255) / 256);
    const int nb_c = (int)(((long long)E + CH - 1) / CH);

    // ---- prep + binning + fused CSR build (4 dispatches) ----
    k_prep<<<128, 256, 0, stream>>>(W1, W2, wt1, wt2, bcnt, dcnt, NBKT);
    k_bincount_scan<<<256, 256, 0, stream>>>(dst, bcnt, bofs, bcur, dcnt, E, NBKT, 256);
    k_binfill<<<nb_c, 256, 0, stream>>>(src, dst, bcur, recs, E, NBKT);
    k_fill_all<<<NBKT, 256, 0, stream>>>(recs, bofs, dinv, ofs, col, N, E);

    // ---- layer 1: ts = dinv*(x@W1); h16 = relu(b1 + dinv*(ts[d] + sum ts[col])) ----
    k_gemm_mfma<0><<<nb_g, 256, 0, stream>>>(x, wt1, dinv, t, N);
    k_agg_csr<1><<<nb_a, 256, 0, stream>>>(ofs, col, dinv, (const half4v*)t, b1, h16, N);

    // ---- layer 2: ts = dinv*(h16@W2); out = b2 + dinv*(ts[d] + sum ts[col]) ----
    k_gemm_mfma<1><<<nb_g, 256, 0, stream>>>(h16, wt2, dinv, t, N);
    k_agg_csr<0><<<nb_a, 256, 0, stream>>>(ofs, col, dinv, (const half4v*)t, b2, out, N);
}